// Round 4
// baseline (283.862 us; speedup 1.0000x reference)
//
#include <hip/hip_runtime.h>

#define NPTS 40000
#define BDIM 4
#define FIN  128
#define CCH  128
#define DVOX 16
#define SVOL 4096   // 16*16*16
#define OROW 259    // FIN + CCH + 3

typedef float fx4 __attribute__((ext_vector_type(4)));
typedef float fx2 __attribute__((ext_vector_type(2)));
typedef int   ix4 __attribute__((ext_vector_type(4)));

// ---------------------------------------------------------------------------
// Kernel T: transpose conv [B,128,4096] -> convt [B,4096,128] so that the
// per-corner gather reads 128 consecutive channels (coalesced).
// ---------------------------------------------------------------------------
__global__ __launch_bounds__(256) void transpose_conv(const float* __restrict__ conv,
                                                      float* __restrict__ convt) {
    __shared__ float tile[128][65];           // +1 pad: conflict-free both phases
    const int b  = blockIdx.y;
    const int s0 = blockIdx.x * 64;
    const int t  = threadIdx.x;

    const float* src = conv + (size_t)b * 128 * SVOL;
    #pragma unroll
    for (int i = 0; i < 32; ++i) {
        int e  = t + 256 * i;                 // 8192 elements
        int c  = e >> 6;                      // 0..127
        int sl = e & 63;                      // coalesced along s
        tile[c][sl] = src[(size_t)c * SVOL + s0 + sl];
    }
    __syncthreads();
    float* dst = convt + ((size_t)b * SVOL + s0) * 128;
    #pragma unroll
    for (int i = 0; i < 32; ++i) {
        int e  = t + 256 * i;
        int sl = e >> 7;                      // 0..63
        int c  = e & 127;                     // coalesced along c
        dst[(size_t)sl * 128 + c] = tile[c][sl];
    }
}

// ---------------------------------------------------------------------------
// Kernel M: fused projection + trilinear sample + concat write.
// Block = 256 threads, 64 points. 1D grid of 2504; blockIdx decodes to
// (batch, tile) so that each XCD (bid & 7) touches exactly ONE batch's 2 MB
// transposed volume -> gathers stay in that XCD's 4 MiB L2.
// LDS is only ~7 KB (no x tile): x is read straight to registers for the
// projection and re-read from L2 for the x->out copy.
// ---------------------------------------------------------------------------
template <bool TR>
__global__ __launch_bounds__(256, 6) void igsc_main(const float* __restrict__ x,
                                                    const float* __restrict__ vol,
                                                    const float* __restrict__ Wm,
                                                    float* __restrict__ out,
                                                    float* __restrict__ pos_out) {
    __shared__ float Ws[4 * 100];   // W chunked per quad q, padded: q -> [q*100, q*100+96)
    __shared__ float wgt[64][8];
    __shared__ int   idx8[64][8];
    __shared__ float ps[64][3];

    const int t    = threadIdx.x;
    const int lid  = blockIdx.x;
    const int xcd  = lid & 7;            // dispatch round-robin -> XCD id (heuristic)
    const int b    = xcd >> 1;           // 2 XCDs per batch
    const int slot = lid >> 3;           // 0..312
    const int tile = slot + (xcd & 1) * 313;
    if (tile >= 625) return;             // block-uniform, before any sync
    const int p0 = tile * 64;

    // ---- stage W into padded per-quad layout ----
    for (int i = t; i < 384; i += 256) {
        int f = i / 3, c = i - 3 * f;    // f in [0,128), c in [0,3)
        Ws[(f >> 5) * 100 + (f & 31) * 3 + c] = Wm[i];
    }
    __syncthreads();

    // ---- phase 1: projection. 4 threads/point; thread reads one 128B line ----
    {
        const int p = t >> 2, q = t & 3;
        const float* xr = x + ((size_t)b * NPTS + p0 + p) * FIN + q * 32;
        fx4 xv[8];
        #pragma unroll
        for (int j = 0; j < 8; ++j) xv[j] = ((const fx4*)xr)[j];   // 1 cache line
        const float* wq = &Ws[q * 100];
        float a0 = 0.f, a1 = 0.f, a2 = 0.f;
        #pragma unroll
        for (int j = 0; j < 8; ++j) {
            #pragma unroll
            for (int e = 0; e < 4; ++e) {
                float xval = xv[j][e];
                int   fl   = j * 4 + e;
                a0 = fmaf(xval, wq[fl * 3 + 0], a0);
                a1 = fmaf(xval, wq[fl * 3 + 1], a1);
                a2 = fmaf(xval, wq[fl * 3 + 2], a2);
            }
        }
        a0 += __shfl_xor(a0, 1); a0 += __shfl_xor(a0, 2);
        a1 += __shfl_xor(a1, 1); a1 += __shfl_xor(a1, 2);
        a2 += __shfl_xor(a2, 1); a2 += __shfl_xor(a2, 2);

        if (q == 0) {
            ps[p][0] = a0; ps[p][1] = a1; ps[p][2] = a2;
            // reference rounding: g = 2p-1; i = (g+1)*0.5*(dim-1)
            float gx = 2.f * a0 - 1.f, gy = 2.f * a1 - 1.f, gz = 2.f * a2 - 1.f;
            float ix = (gx + 1.f) * 0.5f * 15.f;
            float iy = (gy + 1.f) * 0.5f * 15.f;
            float iz = (gz + 1.f) * 0.5f * 15.f;
            float x0f = floorf(ix), y0f = floorf(iy), z0f = floorf(iz);
            float fx = ix - x0f, fy = iy - y0f, fz = iz - z0f;
            int x0 = (int)x0f, y0 = (int)y0f, z0 = (int)z0f;
            fx4 w0v, w1v; ix4 i0v, i1v;
            #pragma unroll
            for (int k = 0; k < 8; ++k) {    // corner order matches reference
                int dx = k & 1, dy = (k >> 1) & 1, dz = k >> 2;
                int xc = x0 + dx, yc = y0 + dy, zc = z0 + dz;
                bool valid = (xc >= 0) & (xc < DVOX) & (yc >= 0) & (yc < DVOX) &
                             (zc >= 0) & (zc < DVOX);
                int xcc = min(max(xc, 0), DVOX - 1);
                int ycc = min(max(yc, 0), DVOX - 1);
                int zcc = min(max(zc, 0), DVOX - 1);
                float wx = dx ? fx : 1.f - fx;
                float wy = dy ? fy : 1.f - fy;
                float wz = dz ? fz : 1.f - fz;
                float wk = valid ? wx * wy * wz : 0.f;
                int   ik = (zcc * DVOX + ycc) * DVOX + xcc;
                if (k < 4) { w0v[k] = wk; i0v[k] = ik; }
                else       { w1v[k - 4] = wk; i1v[k - 4] = ik; }
            }
            *(fx4*)&wgt[p][0]  = w0v; *(fx4*)&wgt[p][4]  = w1v;
            *(ix4*)&idx8[p][0] = i0v; *(ix4*)&idx8[p][4] = i1v;
        }
    }
    __syncthreads();

    // ---- phase 2: sampling + full output row write. Wave owns 16 points ----
    const int wave = t >> 6, lane = t & 63;
    const float* volb = vol + (size_t)b * SVOL * CCH;
    const float* xb   = x + ((size_t)b * NPTS + p0) * FIN;
    #pragma unroll 4
    for (int pp = wave * 16; pp < wave * 16 + 16; ++pp) {
        fx4 w0 = *(const fx4*)&wgt[pp][0];    // broadcast reads
        fx4 w1 = *(const fx4*)&wgt[pp][4];
        ix4 i0 = *(const ix4*)&idx8[pp][0];
        ix4 i1 = *(const ix4*)&idx8[pp][4];
        float acc0 = 0.f, acc1 = 0.f;         // channels 2*lane, 2*lane+1 (TR)
        #pragma unroll
        for (int k = 0; k < 4; ++k) {
            if (w0[k] != 0.f) {               // wave-uniform -> execz skip
                int idx = i0[k];
                if (TR) {
                    fx2 v = *(const fx2*)(volb + idx * CCH + 2 * lane);
                    acc0 = fmaf(w0[k], v.x, acc0);
                    acc1 = fmaf(w0[k], v.y, acc1);
                } else {
                    acc0 = fmaf(w0[k], volb[(2 * lane) * SVOL + idx], acc0);
                    acc1 = fmaf(w0[k], volb[(2 * lane + 1) * SVOL + idx], acc1);
                }
            }
        }
        #pragma unroll
        for (int k = 0; k < 4; ++k) {
            if (w1[k] != 0.f) {
                int idx = i1[k];
                if (TR) {
                    fx2 v = *(const fx2*)(volb + idx * CCH + 2 * lane);
                    acc0 = fmaf(w1[k], v.x, acc0);
                    acc1 = fmaf(w1[k], v.y, acc1);
                } else {
                    acc0 = fmaf(w1[k], volb[(2 * lane) * SVOL + idx], acc0);
                    acc1 = fmaf(w1[k], volb[(2 * lane + 1) * SVOL + idx], acc1);
                }
            }
        }
        size_t row  = (size_t)b * NPTS + p0 + pp;
        float* orow = out + row * OROW;
        // x copy: re-read from L2 (coalesced), write coalesced dwords
        fx2 xv2 = *(const fx2*)(xb + pp * FIN + 2 * lane);
        __builtin_nontemporal_store(xv2.x, &orow[2 * lane]);
        __builtin_nontemporal_store(xv2.y, &orow[2 * lane + 1]);
        __builtin_nontemporal_store(acc0, &orow[128 + 2 * lane]);
        __builtin_nontemporal_store(acc1, &orow[128 + 2 * lane + 1]);
        if (lane < 3) {
            float pv = ps[pp][lane];
            __builtin_nontemporal_store(pv, &orow[256 + lane]);
            __builtin_nontemporal_store(pv, &pos_out[row * 3 + lane]);
        }
    }
}

// ---------------------------------------------------------------------------
extern "C" void kernel_launch(void* const* d_in, const int* in_sizes, int n_in,
                              void* d_out, int out_size, void* d_ws, size_t ws_size,
                              hipStream_t stream) {
    const float* x    = (const float*)d_in[0];
    // d_in[1] = adj (unused by reference)
    const float* conv = (const float*)d_in[2];
    const float* Wm   = (const float*)d_in[3];
    float* out     = (float*)d_out;
    float* pos_out = out + (size_t)BDIM * NPTS * OROW;

    const size_t need = (size_t)BDIM * SVOL * CCH * sizeof(float);
    if (ws_size >= need) {
        float* convt = (float*)d_ws;
        transpose_conv<<<dim3(SVOL / 64, BDIM), 256, 0, stream>>>(conv, convt);
        igsc_main<true><<<dim3(313 * 8), 256, 0, stream>>>(x, convt, Wm, out, pos_out);
    } else {
        igsc_main<false><<<dim3(313 * 8), 256, 0, stream>>>(x, conv, Wm, out, pos_out);
    }
}

// Round 5
// 258.462 us; speedup vs baseline: 1.0983x; 1.0983x over previous
//
#include <hip/hip_runtime.h>

#define NPTS 40000
#define BDIM 4
#define FIN  128
#define CCH  128
#define DVOX 16
#define SVOL 4096   // 16*16*16
#define OROW 259    // FIN + CCH + 3

typedef float fx4 __attribute__((ext_vector_type(4)));
typedef int   ix4 __attribute__((ext_vector_type(4)));

// ---------------------------------------------------------------------------
// Kernel T: transpose conv [B,128,4096] -> convt [B,4096,128] so that the
// per-corner gather reads 128 consecutive channels (coalesced).
// ---------------------------------------------------------------------------
__global__ __launch_bounds__(256) void transpose_conv(const float* __restrict__ conv,
                                                      float* __restrict__ convt) {
    __shared__ float tile[128][65];           // +1 pad: conflict-free both phases
    const int b  = blockIdx.y;
    const int s0 = blockIdx.x * 64;
    const int t  = threadIdx.x;

    const float* src = conv + (size_t)b * 128 * SVOL;
    #pragma unroll
    for (int i = 0; i < 32; ++i) {
        int e  = t + 256 * i;                 // 8192 elements
        int c  = e >> 6;                      // 0..127
        int sl = e & 63;                      // coalesced along s
        tile[c][sl] = src[(size_t)c * SVOL + s0 + sl];
    }
    __syncthreads();
    float* dst = convt + ((size_t)b * SVOL + s0) * 128;
    #pragma unroll
    for (int i = 0; i < 32; ++i) {
        int e  = t + 256 * i;
        int sl = e >> 7;                      // 0..63
        int c  = e & 127;                     // coalesced along c
        dst[(size_t)sl * 128 + c] = tile[c][sl];
    }
}

// ---------------------------------------------------------------------------
// Kernel M: fused projection + trilinear sample + concat write.
// Block = 256 threads, 64 points. blockIdx decodes so each XCD (bid & 7)
// touches ONE batch's 2 MB transposed volume (stays in that XCD's L2).
// Phase 2: 2 points per wave iteration; half-wave per point; lane owns 4
// contiguous channels. One uniform branch per pair skips fully-outside
// points (~60% of pairs); live pairs issue 8 unconditional dwordx4 gathers.
// ---------------------------------------------------------------------------
template <bool TR>
__global__ __launch_bounds__(256, 8) void igsc_main(const float* __restrict__ x,
                                                    const float* __restrict__ vol,
                                                    const float* __restrict__ Wm,
                                                    float* __restrict__ out,
                                                    float* __restrict__ pos_out) {
    __shared__ float Ws[4 * 100];   // W per quad q, padded: q -> [q*100, q*100+96)
    __shared__ float wgt[64][8];
    __shared__ int   idx8[64][8];
    __shared__ float ps[64][4];     // x, y, z, any-valid flag (sum of weights)

    const int t    = threadIdx.x;
    const int lid  = blockIdx.x;
    const int xcd  = lid & 7;            // dispatch round-robin -> XCD id
    const int b    = xcd >> 1;           // 2 XCDs per batch
    const int slot = lid >> 3;           // 0..312
    const int tile = slot + (xcd & 1) * 313;
    if (tile >= 625) return;             // block-uniform, before any sync
    const int p0 = tile * 64;

    // ---- stage W into padded per-quad layout ----
    for (int i = t; i < 384; i += 256) {
        int f = i / 3, c = i - 3 * f;    // f in [0,128), c in [0,3)
        Ws[(f >> 5) * 100 + (f & 31) * 3 + c] = Wm[i];
    }
    __syncthreads();

    // ---- phase 1: projection. 4 threads/point; thread reads one 128B line ----
    {
        const int p = t >> 2, q = t & 3;
        const float* xr = x + ((size_t)b * NPTS + p0 + p) * FIN + q * 32;
        fx4 xv[8];
        #pragma unroll
        for (int j = 0; j < 8; ++j) xv[j] = ((const fx4*)xr)[j];   // 1 cache line
        const float* wq = &Ws[q * 100];
        float a0 = 0.f, a1 = 0.f, a2 = 0.f;
        #pragma unroll
        for (int j = 0; j < 8; ++j) {
            #pragma unroll
            for (int e = 0; e < 4; ++e) {
                float xval = xv[j][e];
                int   fl   = j * 4 + e;
                a0 = fmaf(xval, wq[fl * 3 + 0], a0);
                a1 = fmaf(xval, wq[fl * 3 + 1], a1);
                a2 = fmaf(xval, wq[fl * 3 + 2], a2);
            }
        }
        a0 += __shfl_xor(a0, 1); a0 += __shfl_xor(a0, 2);
        a1 += __shfl_xor(a1, 1); a1 += __shfl_xor(a1, 2);
        a2 += __shfl_xor(a2, 1); a2 += __shfl_xor(a2, 2);

        if (q == 0) {
            // reference rounding: g = 2p-1; i = (g+1)*0.5*(dim-1)
            float gx = 2.f * a0 - 1.f, gy = 2.f * a1 - 1.f, gz = 2.f * a2 - 1.f;
            float ix = (gx + 1.f) * 0.5f * 15.f;
            float iy = (gy + 1.f) * 0.5f * 15.f;
            float iz = (gz + 1.f) * 0.5f * 15.f;
            float x0f = floorf(ix), y0f = floorf(iy), z0f = floorf(iz);
            float fx = ix - x0f, fy = iy - y0f, fz = iz - z0f;
            int x0 = (int)x0f, y0 = (int)y0f, z0 = (int)z0f;
            fx4 w0v, w1v; ix4 i0v, i1v;
            float wsum = 0.f;
            #pragma unroll
            for (int k = 0; k < 8; ++k) {    // corner order matches reference
                int dx = k & 1, dy = (k >> 1) & 1, dz = k >> 2;
                int xc = x0 + dx, yc = y0 + dy, zc = z0 + dz;
                bool valid = (xc >= 0) & (xc < DVOX) & (yc >= 0) & (yc < DVOX) &
                             (zc >= 0) & (zc < DVOX);
                int xcc = min(max(xc, 0), DVOX - 1);
                int ycc = min(max(yc, 0), DVOX - 1);
                int zcc = min(max(zc, 0), DVOX - 1);
                float wx = dx ? fx : 1.f - fx;
                float wy = dy ? fy : 1.f - fy;
                float wz = dz ? fz : 1.f - fz;
                float wk = valid ? wx * wy * wz : 0.f;
                int   ik = (zcc * DVOX + ycc) * DVOX + xcc;
                wsum += wk;
                if (k < 4) { w0v[k] = wk; i0v[k] = ik; }
                else       { w1v[k - 4] = wk; i1v[k - 4] = ik; }
            }
            *(fx4*)&wgt[p][0]  = w0v; *(fx4*)&wgt[p][4]  = w1v;
            *(ix4*)&idx8[p][0] = i0v; *(ix4*)&idx8[p][4] = i1v;
            fx4 pv; pv[0] = a0; pv[1] = a1; pv[2] = a2; pv[3] = wsum;
            *(fx4*)&ps[p][0] = pv;
        }
    }
    __syncthreads();

    // ---- phase 2: sampling + output. 2 points/iter; half-wave per point ----
    const int wave = t >> 6, lane = t & 63;
    const int half = lane >> 5, l = lane & 31;     // lane owns channels 4l..4l+3
    const float* volb = vol + (size_t)b * SVOL * CCH;
    const float* xb   = x + ((size_t)b * NPTS + p0) * FIN;
    #pragma unroll 2
    for (int pp = wave * 16; pp < wave * 16 + 16; pp += 2) {
        const int pA = pp, pB = pp + 1;
        const int p  = half ? pB : pA;
        fx4 w0 = *(const fx4*)&wgt[p][0];          // broadcast per half-wave
        fx4 w1 = *(const fx4*)&wgt[p][4];
        ix4 i0 = *(const ix4*)&idx8[p][0];
        ix4 i1 = *(const ix4*)&idx8[p][4];
        float anyv = ps[pA][3] + ps[pB][3];        // wave-uniform skip test
        fx4 acc = {0.f, 0.f, 0.f, 0.f};
        if (anyv != 0.f) {
            #pragma unroll
            for (int k = 0; k < 4; ++k) {          // 8 unconditional gathers
                fx4 v = *(const fx4*)(volb + i0[k] * CCH + 4 * l);
                acc[0] = fmaf(w0[k], v[0], acc[0]);
                acc[1] = fmaf(w0[k], v[1], acc[1]);
                acc[2] = fmaf(w0[k], v[2], acc[2]);
                acc[3] = fmaf(w0[k], v[3], acc[3]);
            }
            #pragma unroll
            for (int k = 0; k < 4; ++k) {
                fx4 v = *(const fx4*)(volb + i1[k] * CCH + 4 * l);
                acc[0] = fmaf(w1[k], v[0], acc[0]);
                acc[1] = fmaf(w1[k], v[1], acc[1]);
                acc[2] = fmaf(w1[k], v[2], acc[2]);
                acc[3] = fmaf(w1[k], v[3], acc[3]);
            }
        }
        size_t row  = (size_t)b * NPTS + p0 + p;
        float* orow = out + row * OROW;
        fx4 xv = *(const fx4*)(xb + p * FIN + 4 * l);   // aligned L2 re-read
        __builtin_nontemporal_store(xv[0], &orow[4 * l + 0]);
        __builtin_nontemporal_store(xv[1], &orow[4 * l + 1]);
        __builtin_nontemporal_store(xv[2], &orow[4 * l + 2]);
        __builtin_nontemporal_store(xv[3], &orow[4 * l + 3]);
        __builtin_nontemporal_store(acc[0], &orow[128 + 4 * l + 0]);
        __builtin_nontemporal_store(acc[1], &orow[128 + 4 * l + 1]);
        __builtin_nontemporal_store(acc[2], &orow[128 + 4 * l + 2]);
        __builtin_nontemporal_store(acc[3], &orow[128 + 4 * l + 3]);
        if (l < 3) {
            float pv = ps[p][l];
            __builtin_nontemporal_store(pv, &orow[256 + l]);
            __builtin_nontemporal_store(pv, &pos_out[row * 3 + l]);
        }
    }
}

// ---------------------------------------------------------------------------
extern "C" void kernel_launch(void* const* d_in, const int* in_sizes, int n_in,
                              void* d_out, int out_size, void* d_ws, size_t ws_size,
                              hipStream_t stream) {
    const float* x    = (const float*)d_in[0];
    // d_in[1] = adj (unused by reference)
    const float* conv = (const float*)d_in[2];
    const float* Wm   = (const float*)d_in[3];
    float* out     = (float*)d_out;
    float* pos_out = out + (size_t)BDIM * NPTS * OROW;

    const size_t need = (size_t)BDIM * SVOL * CCH * sizeof(float);
    if (ws_size >= need) {
        float* convt = (float*)d_ws;
        transpose_conv<<<dim3(SVOL / 64, BDIM), 256, 0, stream>>>(conv, convt);
        igsc_main<true><<<dim3(313 * 8), 256, 0, stream>>>(x, convt, Wm, out, pos_out);
    } else {
        igsc_main<false><<<dim3(313 * 8), 256, 0, stream>>>(x, conv, Wm, out, pos_out);
    }
}